// Round 10
// baseline (141.495 us; speedup 1.0000x reference)
//
#include <hip/hip_runtime.h>

#define Bn 32
#define Tn 256
#define Cn 512
#define Ln 25

typedef _Float16 h8 __attribute__((ext_vector_type(8)));
typedef __attribute__((ext_vector_type(4))) float f32x4;

#define SCALE2LOG2E 2.885390081777927f   // 2*log2(e)

#if __has_builtin(__builtin_amdgcn_exp2f)
#define EXP2(x) __builtin_amdgcn_exp2f(x)
#else
#define EXP2(x) __expf(0.69314718056f * (x))
#endif

// sum across 16-lane groups on VALU pipe: xor1, xor2, xor7, xor15 pairings
#define DPP_ADD(v, ctrl) \
    ((v) + __int_as_float(__builtin_amdgcn_update_dpp(0, __float_as_int(v), ctrl, 0xf, 0xf, true)))

// K0: flat copy-convert fp32 -> fp16 for A (8192x512) and W (512x512).
#define NA_OCT (Bn * Tn * Cn / 8)           // 524288
#define NW_OCT (Cn * Cn / 8)                // 32768
__global__ __launch_bounds__(256) void k_convert(
        const float* __restrict__ A, const float* __restrict__ W,
        _Float16* __restrict__ A2, _Float16* __restrict__ W2) {
    int idx = blockIdx.x * 256 + threadIdx.x;
    const float* src;
    _Float16* dst;
    int off;
    if (idx < NA_OCT) { src = A; dst = A2; off = idx * 8; }
    else              { src = W; dst = W2; off = (idx - NA_OCT) * 8; }
    float4 v0 = *(const float4*)&src[off];
    float4 v1 = *(const float4*)&src[off + 4];
    h8 o;
    o[0] = (_Float16)v0.x; o[1] = (_Float16)v0.y;
    o[2] = (_Float16)v0.z; o[3] = (_Float16)v0.w;
    o[4] = (_Float16)v1.x; o[5] = (_Float16)v1.y;
    o[6] = (_Float16)v1.z; o[7] = (_Float16)v1.w;
    *(h8*)&dst[off] = o;
}

// K1: wf = A2·W2^T + bias (fp16 MFMA, K=512, tile 128x64, 4 waves 2m x 2n)
// + FUSED per-c-slice scores epilogue -> sc8 plane blockIdx.x.
// sc8[cx][b][l][t] partial over c in [cx*64, cx*64+64).
#define BM 128
#define BN 64
#define BKg 64
__global__ __launch_bounds__(256) void k_gemm(
        const _Float16* __restrict__ A2, const _Float16* __restrict__ W2,
        const float* __restrict__ bias, float* __restrict__ wf,
        const float* __restrict__ pos, const float* __restrict__ aw,
        float* __restrict__ sc8) {
    __shared__ union {
        struct { _Float16 As[BM * BKg]; _Float16 Ws[BN * BKg]; } g;  // 24 KB
        struct { float scp[2 * BM * Ln]; float posl[Ln * BN]; } e;   // 32 KB
    } su;
    const int tid  = threadIdx.x;
    const int lane = tid & 63;
    const int wv   = tid >> 6;
    const int n0 = blockIdx.x * BN;
    const int m0 = blockIdx.y * BM;
    const int wm = (wv >> 1) * 64;
    const int wn = (wv & 1) * 32;
    const int r = lane & 15, q = lane >> 4;

    // ---- K loop (identical to R6) ----
    const _Float16* gA[4];
    const _Float16* gW[2];
    #pragma unroll
    for (int rr = 0; rr < 4; ++rr) {
        int p = rr * 256 + tid;
        int row = p >> 3, pk = p & 7;
        int lk = pk ^ (row & 7);
        gA[rr] = A2 + (size_t)(m0 + row) * Cn + lk * 8;
    }
    #pragma unroll
    for (int rr = 0; rr < 2; ++rr) {
        int p = rr * 256 + tid;
        int row = p >> 3, pk = p & 7;
        int lk = pk ^ (row & 7);
        gW[rr] = W2 + (size_t)(n0 + row) * Cn + lk * 8;
    }

    f32x4 acc[4][2];
    #pragma unroll
    for (int mi = 0; mi < 4; ++mi)
        #pragma unroll
        for (int ni = 0; ni < 2; ++ni) acc[mi][ni] = (f32x4){0.f, 0.f, 0.f, 0.f};

    for (int kt = 0; kt < Cn / BKg; ++kt) {
        __syncthreads();
        #pragma unroll
        for (int rr = 0; rr < 4; ++rr) {
            __builtin_amdgcn_global_load_lds(
                (const __attribute__((address_space(1))) unsigned int*)gA[rr],
                (__attribute__((address_space(3))) unsigned int*)(su.g.As + (rr * 256 + wv * 64) * 8),
                16, 0, 0);
            gA[rr] += BKg;
        }
        #pragma unroll
        for (int rr = 0; rr < 2; ++rr) {
            __builtin_amdgcn_global_load_lds(
                (const __attribute__((address_space(1))) unsigned int*)gW[rr],
                (__attribute__((address_space(3))) unsigned int*)(su.g.Ws + (rr * 256 + wv * 64) * 8),
                16, 0, 0);
            gW[rr] += BKg;
        }
        __syncthreads();

        h8 af[4][2], bfr[2][2];
        #pragma unroll
        for (int mi = 0; mi < 4; ++mi)
            #pragma unroll
            for (int kk = 0; kk < 2; ++kk) {
                int row = wm + mi * 16 + r;
                int phys = (kk * 4 + q) ^ (r & 7);
                af[mi][kk] = *(const h8*)&su.g.As[row * BKg + phys * 8];
            }
        #pragma unroll
        for (int ni = 0; ni < 2; ++ni)
            #pragma unroll
            for (int kk = 0; kk < 2; ++kk) {
                int row = wn + ni * 16 + r;
                int phys = (kk * 4 + q) ^ (r & 7);
                bfr[ni][kk] = *(const h8*)&su.g.Ws[row * BKg + phys * 8];
            }
        #pragma unroll
        for (int kk = 0; kk < 2; ++kk)
            #pragma unroll
            for (int mi = 0; mi < 4; ++mi)
                #pragma unroll
                for (int ni = 0; ni < 2; ++ni)
                    acc[mi][ni] = __builtin_amdgcn_mfma_f32_16x16x32_f16(
                        af[mi][kk], bfr[ni][kk], acc[mi][ni], 0, 0, 0);
    }

    // ---- wf store; transform acc -> SCALE*(wf) in place ----
    #pragma unroll
    for (int ni = 0; ni < 2; ++ni) {
        const float bv = bias[n0 + wn + ni * 16 + r];
        #pragma unroll
        for (int mi = 0; mi < 4; ++mi)
            #pragma unroll
            for (int reg = 0; reg < 4; ++reg) {
                int row = m0 + wm + mi * 16 + q * 4 + reg;
                int col = n0 + wn + ni * 16 + r;
                float v = acc[mi][ni][reg] + bv;
                wf[(size_t)row * Cn + col] = v;
                acc[mi][ni][reg] = SCALE2LOG2E * v;
            }
    }

    // ---- fused scores epilogue ----
    __syncthreads();                         // all waves done reading As/Ws
    for (int i = tid; i < Ln * BN; i += 256) {
        int l = i >> 6, c = i & 63;
        su.e.posl[i] = pos[l * Cn + n0 + c];
    }
    const float aw0 = aw[n0 + wn + r];
    const float aw1 = aw[n0 + wn + 16 + r];
    const float u0 = -2.f * aw0, u1 = -2.f * aw1;
    const float Ul = aw0 + aw1;
    const int wnb = wv & 1;
    __syncthreads();

    for (int l = 0; l < Ln; ++l) {
        const float p0 = su.e.posl[l * BN + wn + r];
        const float p1 = su.e.posl[l * BN + wn + 16 + r];
        #pragma unroll
        for (int mi = 0; mi < 4; ++mi)
            #pragma unroll
            for (int reg = 0; reg < 4; ++reg) {
                float s = Ul;
                s = fmaf(u0, __builtin_amdgcn_rcpf(
                        1.f + EXP2(fmaf(SCALE2LOG2E, p0, acc[mi][0][reg]))), s);
                s = fmaf(u1, __builtin_amdgcn_rcpf(
                        1.f + EXP2(fmaf(SCALE2LOG2E, p1, acc[mi][1][reg]))), s);
                s = DPP_ADD(s, 0xB1);    // xor 1
                s = DPP_ADD(s, 0x4E);    // xor 2
                s = DPP_ADD(s, 0x141);   // row_half_mirror (xor 7)
                s = DPP_ADD(s, 0x140);   // row_mirror (xor 15)
                if (r == mi * 4 + reg)   // 4 writer lanes (q=0..3), one row each
                    su.e.scp[(wnb * BM + wm + mi * 16 + q * 4 + reg) * Ln + l] = s;
            }
    }
    __syncthreads();

    const int b  = blockIdx.y >> 1;
    const int t0 = (blockIdx.y & 1) * BM;
    float* plane = sc8 + ((size_t)blockIdx.x * Bn + b) * (Ln * Tn);
    for (int i = tid; i < BM * Ln; i += 256) {
        int l = i >> 7, row = i & 127;
        float v = su.e.scp[row * Ln + l] + su.e.scp[(BM + row) * Ln + l];
        plane[l * Tn + t0 + row] = v;
    }
}

// K3: sum 8 score planes, softmax over t; out[b][l][c] = sum_t p[l][t]*wf[b][t][c]
// 512 threads (8 waves), block per (c-chunk of 64, b).
__global__ __launch_bounds__(512) void k_pvam(
        const float* __restrict__ wf, const float* __restrict__ sc8,
        float* __restrict__ out) {
    __shared__ float buf[8 * Ln * 64];       // 51.2 KB: scores staging, then reduction
    __shared__ float pT[Tn][28];             // 28.7 KB
    const int tid = threadIdx.x;
    const int cx  = blockIdx.x;
    const int b   = blockIdx.y;

    const size_t PL = (size_t)Bn * Ln * Tn;  // 204800
    const float* sc = sc8 + (size_t)b * (Ln * Tn);
    for (int i = tid * 4; i < Ln * Tn; i += 2048) {
        float4 v = *(const float4*)&sc[i];
        #pragma unroll
        for (int p = 1; p < 8; ++p) {
            float4 s = *(const float4*)&sc[p * PL + i];
            v.x += s.x; v.y += s.y; v.z += s.z; v.w += s.w;
        }
        *(float4*)&buf[i] = v;
    }
    __syncthreads();

    const int lane = tid & 63;
    const int wv   = tid >> 6;

    for (int l = wv; l < Ln; l += 8) {
        float v0 = buf[l * Tn + lane];
        float v1 = buf[l * Tn + 64 + lane];
        float v2 = buf[l * Tn + 128 + lane];
        float v3 = buf[l * Tn + 192 + lane];
        float m = fmaxf(fmaxf(v0, v1), fmaxf(v2, v3));
        #pragma unroll
        for (int o = 32; o > 0; o >>= 1) m = fmaxf(m, __shfl_xor(m, o));
        float e0 = __expf(v0 - m), e1 = __expf(v1 - m);
        float e2 = __expf(v2 - m), e3 = __expf(v3 - m);
        float s = e0 + e1 + e2 + e3;
        #pragma unroll
        for (int o = 32; o > 0; o >>= 1) s += __shfl_xor(s, o);
        float rs = __builtin_amdgcn_rcpf(s);
        pT[lane][l]       = e0 * rs;
        pT[64 + lane][l]  = e1 * rs;
        pT[128 + lane][l] = e2 * rs;
        pT[192 + lane][l] = e3 * rs;
    }
    __syncthreads();

    const int c = cx * 64 + lane;
    float acc[Ln];
    #pragma unroll
    for (int l = 0; l < Ln; ++l) acc[l] = 0.f;

    const float* wfp = wf + (b * Tn + wv * 32) * Cn + c;
    for (int tt = 0; tt < 32; ++tt) {
        float w = wfp[tt * Cn];
        const float* pp = &pT[wv * 32 + tt][0];
        float p[Ln];
        *(float4*)&p[0]  = *(const float4*)&pp[0];
        *(float4*)&p[4]  = *(const float4*)&pp[4];
        *(float4*)&p[8]  = *(const float4*)&pp[8];
        *(float4*)&p[12] = *(const float4*)&pp[12];
        *(float4*)&p[16] = *(const float4*)&pp[16];
        *(float4*)&p[20] = *(const float4*)&pp[20];
        p[24] = pp[24];
        #pragma unroll
        for (int l = 0; l < Ln; ++l) acc[l] = fmaf(p[l], w, acc[l]);
    }

    __syncthreads();
    #pragma unroll
    for (int l = 0; l < Ln; ++l)
        buf[(wv * Ln + l) * 64 + lane] = acc[l];
    __syncthreads();
    for (int idx = tid; idx < Ln * 64; idx += 512) {
        int l = idx >> 6, cc = idx & 63;
        float v = 0.f;
        #pragma unroll
        for (int w = 0; w < 8; ++w) v += buf[(w * Ln + l) * 64 + cc];
        out[(b * Ln + l) * Cn + cx * 64 + cc] = v;
    }
}

extern "C" void kernel_launch(void* const* d_in, const int* in_sizes, int n_in,
                              void* d_out, int out_size, void* d_ws, size_t ws_size,
                              hipStream_t stream) {
    const float* A    = (const float*)d_in[0];
    const float* W    = (const float*)d_in[1];
    const float* bias = (const float*)d_in[2];
    const float* pos  = (const float*)d_in[3];
    const float* aw   = (const float*)d_in[4];

    char* ws = (char*)d_ws;
    float*     wf  = (float*)ws;                         // 16.78 MB
    float*     sc8 = (float*)(ws + 16777216ull);         // 8 planes, 6.55 MB
    _Float16*  A2  = (_Float16*)(ws + 23330816ull);      // 8.39 MB
    _Float16*  W2  = (_Float16*)(ws + 31719424ull);      // 0.52 MB
    float* out = (float*)d_out;

    k_convert<<<(NA_OCT + NW_OCT) / 256, 256, 0, stream>>>(A, W, A2, W2);
    k_gemm<<<dim3(Cn / BN, (Bn * Tn) / BM), 256, 0, stream>>>(A2, W2, bias, wf, pos, aw, sc8);
    k_pvam<<<dim3(Cn / 64, Bn), 512, 0, stream>>>(wf, sc8, out);
}

// Round 11
// 120.733 us; speedup vs baseline: 1.1720x; 1.1720x over previous
//
#include <hip/hip_runtime.h>

#define Bn 32
#define Tn 256
#define Cn 512
#define Ln 25

typedef _Float16 h8 __attribute__((ext_vector_type(8)));
typedef __attribute__((ext_vector_type(4))) float f32x4;

#define SCALE2LOG2E 2.885390081777927f   // 2*log2(e)

#if __has_builtin(__builtin_amdgcn_exp2f)
#define EXP2(x) __builtin_amdgcn_exp2f(x)
#else
#define EXP2(x) __expf(0.69314718056f * (x))
#endif

// sum across 16-lane groups on VALU pipe: xor1, xor2, xor7, xor15 pairings
#define DPP_ADD(v, ctrl) \
    ((v) + __int_as_float(__builtin_amdgcn_update_dpp(0, __float_as_int(v), ctrl, 0xf, 0xf, true)))

__device__ __forceinline__ float tanh_fast(float x) {
    // tanh(x) = 1 - 2/(1 + exp2(2*log2e*x)); saturates safely
    float e = EXP2(SCALE2LOG2E * x);
    return fmaf(-2.f, __builtin_amdgcn_rcpf(1.f + e), 1.f);
}

// K0: copy-convert A,W fp32->fp16 + precompute TP = tanh(pos) (fp32).
#define NA_OCT (Bn * Tn * Cn / 8)           // 524288
#define NW_OCT (Cn * Cn / 8)                // 32768
#define NP_OCT (Ln * Cn / 8)                // 1600
__global__ __launch_bounds__(256) void k_convert(
        const float* __restrict__ A, const float* __restrict__ W,
        const float* __restrict__ pos,
        _Float16* __restrict__ A2, _Float16* __restrict__ W2,
        float* __restrict__ TP) {
    int idx = blockIdx.x * 256 + threadIdx.x;
    if (idx < NA_OCT + NW_OCT) {
        const float* src;
        _Float16* dst;
        int off;
        if (idx < NA_OCT) { src = A; dst = A2; off = idx * 8; }
        else              { src = W; dst = W2; off = (idx - NA_OCT) * 8; }
        float4 v0 = *(const float4*)&src[off];
        float4 v1 = *(const float4*)&src[off + 4];
        h8 o;
        o[0] = (_Float16)v0.x; o[1] = (_Float16)v0.y;
        o[2] = (_Float16)v0.z; o[3] = (_Float16)v0.w;
        o[4] = (_Float16)v1.x; o[5] = (_Float16)v1.y;
        o[6] = (_Float16)v1.z; o[7] = (_Float16)v1.w;
        *(h8*)&dst[off] = o;
    } else if (idx < NA_OCT + NW_OCT + NP_OCT) {
        int off = (idx - NA_OCT - NW_OCT) * 8;
        float4 v0 = *(const float4*)&pos[off];
        float4 v1 = *(const float4*)&pos[off + 4];
        float4 t0, t1;
        t0.x = tanh_fast(v0.x); t0.y = tanh_fast(v0.y);
        t0.z = tanh_fast(v0.z); t0.w = tanh_fast(v0.w);
        t1.x = tanh_fast(v1.x); t1.y = tanh_fast(v1.y);
        t1.z = tanh_fast(v1.z); t1.w = tanh_fast(v1.w);
        *(float4*)&TP[off] = t0;
        *(float4*)&TP[off + 4] = t1;
    }
}

// K1: wf[m][n] = sum_k A2[m][k]*W2[n][k] + bias[n]   (fp16 MFMA, K=512)
// Tile 128x64, BK=64 halves, 4 waves in 2x2. XOR-swizzled LDS (chunk = 16B):
// logical chunk lk of row stored at phys pk = lk ^ (row&7).   [R6-identical]
#define BM 128
#define BN 64
#define BKg 64
__global__ __launch_bounds__(256) void k_gemm(
        const _Float16* __restrict__ A2, const _Float16* __restrict__ W2,
        const float* __restrict__ bias, float* __restrict__ wf) {
    __shared__ _Float16 As[BM * BKg];   // 16 KB
    __shared__ _Float16 Ws[BN * BKg];   // 8 KB
    const int tid  = threadIdx.x;
    const int lane = tid & 63;
    const int wv   = tid >> 6;
    const int m0 = blockIdx.y * BM;
    const int n0 = blockIdx.x * BN;
    const int wm = (wv >> 1) * 64;
    const int wn = (wv & 1) * 32;
    const int r = lane & 15, q = lane >> 4;

    const _Float16* gA[4];
    const _Float16* gW[2];
    #pragma unroll
    for (int rr = 0; rr < 4; ++rr) {
        int p = rr * 256 + tid;
        int row = p >> 3, pk = p & 7;
        int lk = pk ^ (row & 7);
        gA[rr] = A2 + (size_t)(m0 + row) * Cn + lk * 8;
    }
    #pragma unroll
    for (int rr = 0; rr < 2; ++rr) {
        int p = rr * 256 + tid;
        int row = p >> 3, pk = p & 7;
        int lk = pk ^ (row & 7);
        gW[rr] = W2 + (size_t)(n0 + row) * Cn + lk * 8;
    }

    f32x4 acc[4][2];
    #pragma unroll
    for (int mi = 0; mi < 4; ++mi)
        #pragma unroll
        for (int ni = 0; ni < 2; ++ni) acc[mi][ni] = (f32x4){0.f, 0.f, 0.f, 0.f};

    for (int kt = 0; kt < Cn / BKg; ++kt) {
        __syncthreads();
        #pragma unroll
        for (int rr = 0; rr < 4; ++rr) {
            __builtin_amdgcn_global_load_lds(
                (const __attribute__((address_space(1))) unsigned int*)gA[rr],
                (__attribute__((address_space(3))) unsigned int*)(As + (rr * 256 + wv * 64) * 8),
                16, 0, 0);
            gA[rr] += BKg;
        }
        #pragma unroll
        for (int rr = 0; rr < 2; ++rr) {
            __builtin_amdgcn_global_load_lds(
                (const __attribute__((address_space(1))) unsigned int*)gW[rr],
                (__attribute__((address_space(3))) unsigned int*)(Ws + (rr * 256 + wv * 64) * 8),
                16, 0, 0);
            gW[rr] += BKg;
        }
        __syncthreads();

        h8 af[4][2], bfr[2][2];
        #pragma unroll
        for (int mi = 0; mi < 4; ++mi)
            #pragma unroll
            for (int kk = 0; kk < 2; ++kk) {
                int row = wm + mi * 16 + r;
                int phys = (kk * 4 + q) ^ (r & 7);
                af[mi][kk] = *(const h8*)&As[row * BKg + phys * 8];
            }
        #pragma unroll
        for (int ni = 0; ni < 2; ++ni)
            #pragma unroll
            for (int kk = 0; kk < 2; ++kk) {
                int row = wn + ni * 16 + r;
                int phys = (kk * 4 + q) ^ (r & 7);
                bfr[ni][kk] = *(const h8*)&Ws[row * BKg + phys * 8];
            }
        #pragma unroll
        for (int kk = 0; kk < 2; ++kk)
            #pragma unroll
            for (int mi = 0; mi < 4; ++mi)
                #pragma unroll
                for (int ni = 0; ni < 2; ++ni)
                    acc[mi][ni] = __builtin_amdgcn_mfma_f32_16x16x32_f16(
                        af[mi][kk], bfr[ni][kk], acc[mi][ni], 0, 0, 0);
    }

    #pragma unroll
    for (int ni = 0; ni < 2; ++ni) {
        const float bv = bias[n0 + wn + ni * 16 + r];
        #pragma unroll
        for (int mi = 0; mi < 4; ++mi)
            #pragma unroll
            for (int reg = 0; reg < 4; ++reg) {
                int row = m0 + wm + mi * 16 + q * 4 + reg;
                int col = n0 + wn + ni * 16 + r;
                wf[(size_t)row * Cn + col] = acc[mi][ni][reg] + bv;
            }
    }
}

// K2: scores[b][l][t] = sum_c tanh(wf+pos)*aw
//   via tanh addition: tanh(w+p) = (tw + tp) / (1 + tw*tp), tp precomputed.
// Inner loop: 1 SFU + 4 VALU per element (was 2 SFU + 3 VALU).
// 512 thr = 8 waves: wave = (t_local 0..3) x (c-half 0..1); 4 c-elems/lane;
// 5x5 unrolled l-loop; DPP 16-lane reduce; LDS partial combine.
__global__ __launch_bounds__(512) void k_scores(
        const float* __restrict__ wf, const float* __restrict__ TP,
        const float* __restrict__ aw, float* __restrict__ scores) {
    __shared__ float part[4 * Ln * 8];       // 3.2 KB
    const int tid  = threadIdx.x;
    const int lane = tid & 63;
    const int wv   = tid >> 6;
    const int tl   = wv >> 1;                // local t 0..3
    const int ch   = wv & 1;                 // c half
    const int t    = blockIdx.x * 4 + tl;
    const int b    = blockIdx.y;
    const int co   = ch * 256 + lane * 4;

    const float4 w = *(const float4*)&wf[(b * Tn + t) * Cn + co];
    float4 tw;
    tw.x = tanh_fast(w.x); tw.y = tanh_fast(w.y);
    tw.z = tanh_fast(w.z); tw.w = tanh_fast(w.w);
    const float4 a = *(const float4*)&aw[co];

    const float* pp = TP + co;
    float* prt = &part[tl * Ln * 8 + ch * 4 + (lane >> 4)];
    const bool writer = ((lane & 15) == 0);

    #pragma unroll
    for (int lo = 0; lo < 5; ++lo) {
        float4 pv[5];
        #pragma unroll
        for (int j = 0; j < 5; ++j)
            pv[j] = *(const float4*)(pp + (lo * 5 + j) * Cn);
        #pragma unroll
        for (int j = 0; j < 5; ++j) {
            const float4 p = pv[j];
            float s;
            {
                float d = fmaf(tw.x, p.x, 1.f);
                float n = tw.x + p.x;
                s = a.x * n * __builtin_amdgcn_rcpf(d);
            }
            {
                float d = fmaf(tw.y, p.y, 1.f);
                float n = tw.y + p.y;
                s = fmaf(a.y * n, __builtin_amdgcn_rcpf(d), s);
            }
            {
                float d = fmaf(tw.z, p.z, 1.f);
                float n = tw.z + p.z;
                s = fmaf(a.z * n, __builtin_amdgcn_rcpf(d), s);
            }
            {
                float d = fmaf(tw.w, p.w, 1.f);
                float n = tw.w + p.w;
                s = fmaf(a.w * n, __builtin_amdgcn_rcpf(d), s);
            }
            s = DPP_ADD(s, 0xB1);    // xor 1
            s = DPP_ADD(s, 0x4E);    // xor 2
            s = DPP_ADD(s, 0x141);   // row_half_mirror (xor 7)
            s = DPP_ADD(s, 0x140);   // row_mirror (xor 15)
            if (writer) prt[(lo * 5 + j) * 8] = s;
        }
    }
    __syncthreads();
    if (tid < 4 * Ln) {
        int tl2 = tid / Ln, l2 = tid - tl2 * Ln;
        const float* q = &part[(tl2 * Ln + l2) * 8];
        float v = ((q[0] + q[1]) + (q[2] + q[3])) + ((q[4] + q[5]) + (q[6] + q[7]));
        scores[(b * Ln + l2) * Tn + blockIdx.x * 4 + tl2] = v;
    }
}

// K3: softmax over t; out[b][l][c] = sum_t p[l][t] * wf[b][t][c]   [R6-identical]
__global__ __launch_bounds__(512) void k_pvam(
        const float* __restrict__ wf, const float* __restrict__ scores,
        float* __restrict__ out) {
    __shared__ float buf[8 * Ln * 64];       // 51.2 KB: scores staging, then reduction
    __shared__ float pT[Tn][28];             // 28.7 KB
    const int tid = threadIdx.x;
    const int cx  = blockIdx.x;
    const int b   = blockIdx.y;

    const float* sc = scores + b * Ln * Tn;
    for (int i = tid * 4; i < Ln * Tn; i += 2048)
        *(float4*)&buf[i] = *(const float4*)&sc[i];
    __syncthreads();

    const int lane = tid & 63;
    const int wv   = tid >> 6;

    for (int l = wv; l < Ln; l += 8) {
        float v0 = buf[l * Tn + lane];
        float v1 = buf[l * Tn + 64 + lane];
        float v2 = buf[l * Tn + 128 + lane];
        float v3 = buf[l * Tn + 192 + lane];
        float m = fmaxf(fmaxf(v0, v1), fmaxf(v2, v3));
        #pragma unroll
        for (int o = 32; o > 0; o >>= 1) m = fmaxf(m, __shfl_xor(m, o));
        float e0 = __expf(v0 - m), e1 = __expf(v1 - m);
        float e2 = __expf(v2 - m), e3 = __expf(v3 - m);
        float s = e0 + e1 + e2 + e3;
        #pragma unroll
        for (int o = 32; o > 0; o >>= 1) s += __shfl_xor(s, o);
        float rs = __builtin_amdgcn_rcpf(s);
        pT[lane][l]       = e0 * rs;
        pT[64 + lane][l]  = e1 * rs;
        pT[128 + lane][l] = e2 * rs;
        pT[192 + lane][l] = e3 * rs;
    }
    __syncthreads();

    const int c = cx * 64 + lane;
    float acc[Ln];
    #pragma unroll
    for (int l = 0; l < Ln; ++l) acc[l] = 0.f;

    const float* wfp = wf + (b * Tn + wv * 32) * Cn + c;
    for (int tt = 0; tt < 32; ++tt) {
        float w = wfp[tt * Cn];
        const float* pp = &pT[wv * 32 + tt][0];
        float p[Ln];
        *(float4*)&p[0]  = *(const float4*)&pp[0];
        *(float4*)&p[4]  = *(const float4*)&pp[4];
        *(float4*)&p[8]  = *(const float4*)&pp[8];
        *(float4*)&p[12] = *(const float4*)&pp[12];
        *(float4*)&p[16] = *(const float4*)&pp[16];
        *(float4*)&p[20] = *(const float4*)&pp[20];
        p[24] = pp[24];
        #pragma unroll
        for (int l = 0; l < Ln; ++l) acc[l] = fmaf(p[l], w, acc[l]);
    }

    __syncthreads();
    #pragma unroll
    for (int l = 0; l < Ln; ++l)
        buf[(wv * Ln + l) * 64 + lane] = acc[l];
    __syncthreads();
    for (int idx = tid; idx < Ln * 64; idx += 512) {
        int l = idx >> 6, cc = idx & 63;
        float v = 0.f;
        #pragma unroll
        for (int w = 0; w < 8; ++w) v += buf[(w * Ln + l) * 64 + cc];
        out[(b * Ln + l) * Cn + cx * 64 + cc] = v;
    }
}

extern "C" void kernel_launch(void* const* d_in, const int* in_sizes, int n_in,
                              void* d_out, int out_size, void* d_ws, size_t ws_size,
                              hipStream_t stream) {
    const float* A    = (const float*)d_in[0];
    const float* W    = (const float*)d_in[1];
    const float* bias = (const float*)d_in[2];
    const float* pos  = (const float*)d_in[3];
    const float* aw   = (const float*)d_in[4];

    char* ws = (char*)d_ws;
    float*     wf     = (float*)ws;                          // 16.78 MB
    float*     scores = (float*)(ws + 16777216ull);          // 0.82 MB
    _Float16*  A2     = (_Float16*)(ws + 20054016ull);       // 8.39 MB
    _Float16*  W2     = (_Float16*)(ws + 28442624ull);       // 0.52 MB
    float*     TP     = (float*)(ws + 28966912ull);          // 51.2 KB tanh(pos)
    float* out = (float*)d_out;

    const int nconv = (NA_OCT + NW_OCT + NP_OCT + 255) / 256;
    k_convert<<<nconv, 256, 0, stream>>>(A, W, pos, A2, W2, TP);
    k_gemm<<<dim3(Cn / BN, (Bn * Tn) / BM), 256, 0, stream>>>(A2, W2, bias, wf);
    k_scores<<<dim3(Tn / 4, Bn), 512, 0, stream>>>(wf, TP, aw, scores);
    k_pvam<<<dim3(Cn / 64, Bn), 512, 0, stream>>>(wf, scores, out);
}

// Round 12
// 120.505 us; speedup vs baseline: 1.1742x; 1.0019x over previous
//
#include <hip/hip_runtime.h>

#define Bn 32
#define Tn 256
#define Cn 512
#define Ln 25

typedef _Float16 h8 __attribute__((ext_vector_type(8)));
typedef _Float16 h4 __attribute__((ext_vector_type(4)));
typedef __attribute__((ext_vector_type(4))) float f32x4;

#define SCALE2LOG2E 2.885390081777927f   // 2*log2(e)

#if __has_builtin(__builtin_amdgcn_exp2f)
#define EXP2(x) __builtin_amdgcn_exp2f(x)
#else
#define EXP2(x) __expf(0.69314718056f * (x))
#endif

// sum across 16-lane groups on VALU pipe: xor1, xor2, xor7, xor15 pairings
#define DPP_ADD(v, ctrl) \
    ((v) + __int_as_float(__builtin_amdgcn_update_dpp(0, __float_as_int(v), ctrl, 0xf, 0xf, true)))

__device__ __forceinline__ float tanh_fast(float x) {
    float e = EXP2(SCALE2LOG2E * x);
    return fmaf(-2.f, __builtin_amdgcn_rcpf(1.f + e), 1.f);
}

// K0: copy-convert A,W fp32->fp16 + precompute TP = tanh(pos) (fp32).
#define NA_OCT (Bn * Tn * Cn / 8)           // 524288
#define NW_OCT (Cn * Cn / 8)                // 32768
#define NP_OCT (Ln * Cn / 8)                // 1600
__global__ __launch_bounds__(256) void k_convert(
        const float* __restrict__ A, const float* __restrict__ W,
        const float* __restrict__ pos,
        _Float16* __restrict__ A2, _Float16* __restrict__ W2,
        float* __restrict__ TP) {
    int idx = blockIdx.x * 256 + threadIdx.x;
    if (idx < NA_OCT + NW_OCT) {
        const float* src;
        _Float16* dst;
        int off;
        if (idx < NA_OCT) { src = A; dst = A2; off = idx * 8; }
        else              { src = W; dst = W2; off = (idx - NA_OCT) * 8; }
        float4 v0 = *(const float4*)&src[off];
        float4 v1 = *(const float4*)&src[off + 4];
        h8 o;
        o[0] = (_Float16)v0.x; o[1] = (_Float16)v0.y;
        o[2] = (_Float16)v0.z; o[3] = (_Float16)v0.w;
        o[4] = (_Float16)v1.x; o[5] = (_Float16)v1.y;
        o[6] = (_Float16)v1.z; o[7] = (_Float16)v1.w;
        *(h8*)&dst[off] = o;
    } else if (idx < NA_OCT + NW_OCT + NP_OCT) {
        int off = (idx - NA_OCT - NW_OCT) * 8;
        float4 v0 = *(const float4*)&pos[off];
        float4 v1 = *(const float4*)&pos[off + 4];
        float4 t0, t1;
        t0.x = tanh_fast(v0.x); t0.y = tanh_fast(v0.y);
        t0.z = tanh_fast(v0.z); t0.w = tanh_fast(v0.w);
        t1.x = tanh_fast(v1.x); t1.y = tanh_fast(v1.y);
        t1.z = tanh_fast(v1.z); t1.w = tanh_fast(v1.w);
        *(float4*)&TP[off] = t0;
        *(float4*)&TP[off + 4] = t1;
    }
}

// K1: wf[m][n] = sum_k A2[m][k]*W2[n][k] + bias[n]   (fp16 MFMA, K=512)
// R6/R11 structure; wf now stored as fp16.
#define BM 128
#define BN 64
#define BKg 64
__global__ __launch_bounds__(256) void k_gemm(
        const _Float16* __restrict__ A2, const _Float16* __restrict__ W2,
        const float* __restrict__ bias, _Float16* __restrict__ wf) {
    __shared__ _Float16 As[BM * BKg];   // 16 KB
    __shared__ _Float16 Ws[BN * BKg];   // 8 KB
    const int tid  = threadIdx.x;
    const int lane = tid & 63;
    const int wv   = tid >> 6;
    const int m0 = blockIdx.y * BM;
    const int n0 = blockIdx.x * BN;
    const int wm = (wv >> 1) * 64;
    const int wn = (wv & 1) * 32;
    const int r = lane & 15, q = lane >> 4;

    const _Float16* gA[4];
    const _Float16* gW[2];
    #pragma unroll
    for (int rr = 0; rr < 4; ++rr) {
        int p = rr * 256 + tid;
        int row = p >> 3, pk = p & 7;
        int lk = pk ^ (row & 7);
        gA[rr] = A2 + (size_t)(m0 + row) * Cn + lk * 8;
    }
    #pragma unroll
    for (int rr = 0; rr < 2; ++rr) {
        int p = rr * 256 + tid;
        int row = p >> 3, pk = p & 7;
        int lk = pk ^ (row & 7);
        gW[rr] = W2 + (size_t)(n0 + row) * Cn + lk * 8;
    }

    f32x4 acc[4][2];
    #pragma unroll
    for (int mi = 0; mi < 4; ++mi)
        #pragma unroll
        for (int ni = 0; ni < 2; ++ni) acc[mi][ni] = (f32x4){0.f, 0.f, 0.f, 0.f};

    for (int kt = 0; kt < Cn / BKg; ++kt) {
        __syncthreads();
        #pragma unroll
        for (int rr = 0; rr < 4; ++rr) {
            __builtin_amdgcn_global_load_lds(
                (const __attribute__((address_space(1))) unsigned int*)gA[rr],
                (__attribute__((address_space(3))) unsigned int*)(As + (rr * 256 + wv * 64) * 8),
                16, 0, 0);
            gA[rr] += BKg;
        }
        #pragma unroll
        for (int rr = 0; rr < 2; ++rr) {
            __builtin_amdgcn_global_load_lds(
                (const __attribute__((address_space(1))) unsigned int*)gW[rr],
                (__attribute__((address_space(3))) unsigned int*)(Ws + (rr * 256 + wv * 64) * 8),
                16, 0, 0);
            gW[rr] += BKg;
        }
        __syncthreads();

        h8 af[4][2], bfr[2][2];
        #pragma unroll
        for (int mi = 0; mi < 4; ++mi)
            #pragma unroll
            for (int kk = 0; kk < 2; ++kk) {
                int row = wm + mi * 16 + r;
                int phys = (kk * 4 + q) ^ (r & 7);
                af[mi][kk] = *(const h8*)&As[row * BKg + phys * 8];
            }
        #pragma unroll
        for (int ni = 0; ni < 2; ++ni)
            #pragma unroll
            for (int kk = 0; kk < 2; ++kk) {
                int row = wn + ni * 16 + r;
                int phys = (kk * 4 + q) ^ (r & 7);
                bfr[ni][kk] = *(const h8*)&Ws[row * BKg + phys * 8];
            }
        #pragma unroll
        for (int kk = 0; kk < 2; ++kk)
            #pragma unroll
            for (int mi = 0; mi < 4; ++mi)
                #pragma unroll
                for (int ni = 0; ni < 2; ++ni)
                    acc[mi][ni] = __builtin_amdgcn_mfma_f32_16x16x32_f16(
                        af[mi][kk], bfr[ni][kk], acc[mi][ni], 0, 0, 0);
    }

    #pragma unroll
    for (int ni = 0; ni < 2; ++ni) {
        const float bv = bias[n0 + wn + ni * 16 + r];
        #pragma unroll
        for (int mi = 0; mi < 4; ++mi)
            #pragma unroll
            for (int reg = 0; reg < 4; ++reg) {
                int row = m0 + wm + mi * 16 + q * 4 + reg;
                int col = n0 + wn + ni * 16 + r;
                wf[(size_t)row * Cn + col] = (_Float16)(acc[mi][ni][reg] + bv);
            }
    }
}

// K2: scores via tanh addition formula; wf read as fp16 (8 B/lane).
__global__ __launch_bounds__(512) void k_scores(
        const _Float16* __restrict__ wf, const float* __restrict__ TP,
        const float* __restrict__ aw, float* __restrict__ scores) {
    __shared__ float part[4 * Ln * 8];       // 3.2 KB
    const int tid  = threadIdx.x;
    const int lane = tid & 63;
    const int wv   = tid >> 6;
    const int tl   = wv >> 1;                // local t 0..3
    const int ch   = wv & 1;                 // c half
    const int t    = blockIdx.x * 4 + tl;
    const int b    = blockIdx.y;
    const int co   = ch * 256 + lane * 4;

    const h4 wh = *(const h4*)&wf[(size_t)(b * Tn + t) * Cn + co];
    float4 tw;
    tw.x = tanh_fast((float)wh[0]); tw.y = tanh_fast((float)wh[1]);
    tw.z = tanh_fast((float)wh[2]); tw.w = tanh_fast((float)wh[3]);
    const float4 a = *(const float4*)&aw[co];

    const float* pp = TP + co;
    float* prt = &part[tl * Ln * 8 + ch * 4 + (lane >> 4)];
    const bool writer = ((lane & 15) == 0);

    #pragma unroll
    for (int lo = 0; lo < 5; ++lo) {
        float4 pv[5];
        #pragma unroll
        for (int j = 0; j < 5; ++j)
            pv[j] = *(const float4*)(pp + (lo * 5 + j) * Cn);
        #pragma unroll
        for (int j = 0; j < 5; ++j) {
            const float4 p = pv[j];
            float s;
            {
                float d = fmaf(tw.x, p.x, 1.f);
                s = a.x * (tw.x + p.x) * __builtin_amdgcn_rcpf(d);
            }
            {
                float d = fmaf(tw.y, p.y, 1.f);
                s = fmaf(a.y * (tw.y + p.y), __builtin_amdgcn_rcpf(d), s);
            }
            {
                float d = fmaf(tw.z, p.z, 1.f);
                s = fmaf(a.z * (tw.z + p.z), __builtin_amdgcn_rcpf(d), s);
            }
            {
                float d = fmaf(tw.w, p.w, 1.f);
                s = fmaf(a.w * (tw.w + p.w), __builtin_amdgcn_rcpf(d), s);
            }
            s = DPP_ADD(s, 0xB1);    // xor 1
            s = DPP_ADD(s, 0x4E);    // xor 2
            s = DPP_ADD(s, 0x141);   // row_half_mirror (xor 7)
            s = DPP_ADD(s, 0x140);   // row_mirror (xor 15)
            if (writer) prt[(lo * 5 + j) * 8] = s;
        }
    }
    __syncthreads();
    if (tid < 4 * Ln) {
        int tl2 = tid / Ln, l2 = tid - tl2 * Ln;
        const float* q = &part[(tl2 * Ln + l2) * 8];
        float v = ((q[0] + q[1]) + (q[2] + q[3])) + ((q[4] + q[5]) + (q[6] + q[7]));
        scores[(b * Ln + l2) * Tn + blockIdx.x * 4 + tl2] = v;
    }
}

// K3: softmax over t; out[b][l][c] = sum_t p[l][t] * wf[b][t][c]; wf fp16 reads.
__global__ __launch_bounds__(512) void k_pvam(
        const _Float16* __restrict__ wf, const float* __restrict__ scores,
        float* __restrict__ out) {
    __shared__ float buf[8 * Ln * 64];       // 51.2 KB: scores staging, then reduction
    __shared__ float pT[Tn][28];             // 28.7 KB
    const int tid = threadIdx.x;
    const int cx  = blockIdx.x;
    const int b   = blockIdx.y;

    const float* sc = scores + b * Ln * Tn;
    for (int i = tid * 4; i < Ln * Tn; i += 2048)
        *(float4*)&buf[i] = *(const float4*)&sc[i];
    __syncthreads();

    const int lane = tid & 63;
    const int wv   = tid >> 6;

    for (int l = wv; l < Ln; l += 8) {
        float v0 = buf[l * Tn + lane];
        float v1 = buf[l * Tn + 64 + lane];
        float v2 = buf[l * Tn + 128 + lane];
        float v3 = buf[l * Tn + 192 + lane];
        float m = fmaxf(fmaxf(v0, v1), fmaxf(v2, v3));
        #pragma unroll
        for (int o = 32; o > 0; o >>= 1) m = fmaxf(m, __shfl_xor(m, o));
        float e0 = __expf(v0 - m), e1 = __expf(v1 - m);
        float e2 = __expf(v2 - m), e3 = __expf(v3 - m);
        float s = e0 + e1 + e2 + e3;
        #pragma unroll
        for (int o = 32; o > 0; o >>= 1) s += __shfl_xor(s, o);
        float rs = __builtin_amdgcn_rcpf(s);
        pT[lane][l]       = e0 * rs;
        pT[64 + lane][l]  = e1 * rs;
        pT[128 + lane][l] = e2 * rs;
        pT[192 + lane][l] = e3 * rs;
    }
    __syncthreads();

    const int c = cx * 64 + lane;
    float acc[Ln];
    #pragma unroll
    for (int l = 0; l < Ln; ++l) acc[l] = 0.f;

    const _Float16* wfp = wf + (size_t)(b * Tn + wv * 32) * Cn + c;
    for (int tt = 0; tt < 32; ++tt) {
        float w = (float)wfp[(size_t)tt * Cn];
        const float* pp = &pT[wv * 32 + tt][0];
        float p[Ln];
        *(float4*)&p[0]  = *(const float4*)&pp[0];
        *(float4*)&p[4]  = *(const float4*)&pp[4];
        *(float4*)&p[8]  = *(const float4*)&pp[8];
        *(float4*)&p[12] = *(const float4*)&pp[12];
        *(float4*)&p[16] = *(const float4*)&pp[16];
        *(float4*)&p[20] = *(const float4*)&pp[20];
        p[24] = pp[24];
        #pragma unroll
        for (int l = 0; l < Ln; ++l) acc[l] = fmaf(p[l], w, acc[l]);
    }

    __syncthreads();
    #pragma unroll
    for (int l = 0; l < Ln; ++l)
        buf[(wv * Ln + l) * 64 + lane] = acc[l];
    __syncthreads();
    for (int idx = tid; idx < Ln * 64; idx += 512) {
        int l = idx >> 6, cc = idx & 63;
        float v = 0.f;
        #pragma unroll
        for (int w = 0; w < 8; ++w) v += buf[(w * Ln + l) * 64 + cc];
        out[(b * Ln + l) * Cn + cx * 64 + cc] = v;
    }
}

extern "C" void kernel_launch(void* const* d_in, const int* in_sizes, int n_in,
                              void* d_out, int out_size, void* d_ws, size_t ws_size,
                              hipStream_t stream) {
    const float* A    = (const float*)d_in[0];
    const float* W    = (const float*)d_in[1];
    const float* bias = (const float*)d_in[2];
    const float* pos  = (const float*)d_in[3];
    const float* aw   = (const float*)d_in[4];

    char* ws = (char*)d_ws;
    _Float16*  wf     = (_Float16*)ws;                       // 8.39 MB
    float*     scores = (float*)(ws + 8388608ull);           // 0.82 MB
    _Float16*  A2     = (_Float16*)(ws + 9240576ull);        // 8.39 MB
    _Float16*  W2     = (_Float16*)(ws + 17629184ull);       // 0.52 MB
    float*     TP     = (float*)(ws + 18153472ull);          // 51.2 KB tanh(pos)
    float* out = (float*)d_out;

    const int nconv = (NA_OCT + NW_OCT + NP_OCT + 255) / 256;
    k_convert<<<nconv, 256, 0, stream>>>(A, W, pos, A2, W2, TP);
    k_gemm<<<dim3(Cn / BN, (Bn * Tn) / BM), 256, 0, stream>>>(A2, W2, bias, wf);
    k_scores<<<dim3(Tn / 4, Bn), 512, 0, stream>>>(wf, TP, aw, scores);
    k_pvam<<<dim3(Cn / 64, Bn), 512, 0, stream>>>(wf, scores, out);
}